// Round 1
// baseline (1880.866 us; speedup 1.0000x reference)
//
#include <hip/hip_runtime.h>
#include <hip/hip_bf16.h>
#include <math.h>

#define NTOK   8192   // B*T = 4*2048
#define DM     1024   // d_model
#define DH     4096   // hidden
#define NE     8      // experts

typedef __bf16 bf16;
typedef __bf16 bf16x4 __attribute__((ext_vector_type(4)));
typedef __bf16 bf16x8 __attribute__((ext_vector_type(8)));
typedef float  f32x4  __attribute__((ext_vector_type(4)));

__device__ __forceinline__ void gload16(const void* g, void* l) {
  __builtin_amdgcn_global_load_lds(
      (const __attribute__((address_space(1))) void*)g,
      (__attribute__((address_space(3))) void*)l, 16, 0, 0);
}

// ---------------- fp32 -> bf16 elementwise (x) ----------------
__global__ void convert_x_kernel(const float* __restrict__ src,
                                 bf16* __restrict__ dst, int n4) {
  int stride = gridDim.x * blockDim.x;
  for (int i = blockIdx.x * blockDim.x + threadIdx.x; i < n4; i += stride) {
    float4 v = reinterpret_cast<const float4*>(src)[i];
    bf16x4 o;
    o[0] = (bf16)v.x; o[1] = (bf16)v.y; o[2] = (bf16)v.z; o[3] = (bf16)v.w;
    reinterpret_cast<bf16x4*>(dst)[i] = o;
  }
}

// ------------- fp32 [E][R][C] -> bf16 [E][C][R] tiled transpose -------------
__global__ void transpose_convert_kernel(const float* __restrict__ src,
                                         bf16* __restrict__ dst, int R, int C) {
  __shared__ bf16 tile[64][66];
  int e = blockIdx.z;
  src += (size_t)e * R * C;
  dst += (size_t)e * R * C;
  int c0 = blockIdx.x * 64;
  int r0 = blockIdx.y * 64;
  int lr = threadIdx.x >> 6;   // 0..3
  int lc = threadIdx.x & 63;
#pragma unroll
  for (int i = 0; i < 16; i++) {
    int r = lr + i * 4;
    tile[r][lc] = (bf16)src[(size_t)(r0 + r) * C + c0 + lc];
  }
  __syncthreads();
#pragma unroll
  for (int i = 0; i < 16; i++) {
    int r = lr + i * 4;  // row of dst block (= src col)
    dst[(size_t)(c0 + r) * R + r0 + lc] = tile[lc][r];
  }
}

// ---------------- gating: logits -> top2 -> softmax -> weights[t][8] ----------------
__global__ void gating_kernel(const float* __restrict__ x,
                              const float* __restrict__ gw,
                              const float* __restrict__ gb,
                              float* __restrict__ wts) {
  int wave = threadIdx.x >> 6, lane = threadIdx.x & 63;
  int t = blockIdx.x * 4 + wave;
  const float* xr = x + (size_t)t * DM;
  float acc[8];
#pragma unroll
  for (int e = 0; e < 8; e++) acc[e] = 0.f;
#pragma unroll
  for (int i = 0; i < 16; i++) {
    int d = lane + i * 64;
    float xv = xr[d];
    const float4* g = reinterpret_cast<const float4*>(gw + d * 8);
    float4 g0 = g[0], g1 = g[1];
    acc[0] += xv * g0.x; acc[1] += xv * g0.y; acc[2] += xv * g0.z; acc[3] += xv * g0.w;
    acc[4] += xv * g1.x; acc[5] += xv * g1.y; acc[6] += xv * g1.z; acc[7] += xv * g1.w;
  }
#pragma unroll
  for (int off = 32; off > 0; off >>= 1)
#pragma unroll
    for (int e = 0; e < 8; e++) acc[e] += __shfl_xor(acc[e], off, 64);
  float v[8];
#pragma unroll
  for (int e = 0; e < 8; e++) v[e] = acc[e] + gb[e];
  int i0 = 0; float v0 = v[0];
#pragma unroll
  for (int e = 1; e < 8; e++) if (v[e] > v0) { v0 = v[e]; i0 = e; }
  int i1 = -1; float v1 = -1e30f;
#pragma unroll
  for (int e = 0; e < 8; e++) if (e != i0 && v[e] > v1) { v1 = v[e]; i1 = e; }
  float p1 = expf(v1 - v0);
  float den = 1.f + p1;
  float w0 = 1.f / den, w1 = p1 / den;
  if (lane < 8) wts[t * 8 + lane] = (lane == i0) ? w0 : ((lane == i1) ? w1 : 0.f);
}

// ---------------- bf16 MFMA GEMM: C = A[M,K] * Bt[N,K]^T ----------------
// EPI==0: Hout[m,n] = gelu(C + bias[n])  (bf16 store)
// EPI==1: Out[m,n] += wts[m*8+expert] * (C + bias[n])  (fp32 accumulate)
template <int EPI>
__global__ __launch_bounds__(256) void moe_gemm_kernel(
    const bf16* __restrict__ A, const bf16* __restrict__ Bt,
    const float* __restrict__ bias, bf16* __restrict__ Hout,
    float* __restrict__ Out, const float* __restrict__ wts,
    int expert, int M, int N, int K) {
  constexpr int BM = 128, BN = 128, BK = 64;
  __shared__ __align__(16) bf16 As[BM * BK];
  __shared__ __align__(16) bf16 Bs[BN * BK];
  const int tid = threadIdx.x;
  const int wave = tid >> 6, lane = tid & 63;
  const int nbn = N / BN;
  const int bm0 = (int)(blockIdx.x / nbn) * BM;
  const int bn0 = (int)(blockIdx.x % nbn) * BN;
  const int wm = (wave >> 1) * 64, wn = (wave & 1) * 64;

  f32x4 acc[4][4];
#pragma unroll
  for (int m = 0; m < 4; m++)
#pragma unroll
    for (int n = 0; n < 4; n++)
#pragma unroll
      for (int j = 0; j < 4; j++) acc[m][n][j] = 0.f;

  const int srow = lane >> 3;            // 0..7 within an 8-row chunk
  const int scolb = (lane & 7) << 4;     // byte col 0..112

  for (int kt = 0; kt < K; kt += BK) {
#pragma unroll
    for (int it = 0; it < 4; it++) {
      int chunk = it * 4 + wave;         // wave-uniform
      int row = chunk * 8 + srow;
      int csw = scolb ^ ((row & 7) << 4);  // pre-swizzled global source
      const char* ga = (const char*)A + ((size_t)(bm0 + row) * K + kt) * 2 + csw;
      gload16(ga, (char*)As + chunk * 1024);
      const char* gb = (const char*)Bt + ((size_t)(bn0 + row) * K + kt) * 2 + csw;
      gload16(gb, (char*)Bs + chunk * 1024);
    }
    __syncthreads();
#pragma unroll
    for (int kk = 0; kk < 2; kk++) {
      const int kb = kk * 64 + ((lane >> 4) << 4);  // byte offset of k in row
      bf16x8 af[4], bfv[4];
#pragma unroll
      for (int m = 0; m < 4; m++) {
        int r = wm + m * 16 + (lane & 15);
        af[m] = *(const bf16x8*)((const char*)As + r * 128 + (kb ^ ((r & 7) << 4)));
      }
#pragma unroll
      for (int n = 0; n < 4; n++) {
        int r = wn + n * 16 + (lane & 15);
        bfv[n] = *(const bf16x8*)((const char*)Bs + r * 128 + (kb ^ ((r & 7) << 4)));
      }
#pragma unroll
      for (int m = 0; m < 4; m++)
#pragma unroll
        for (int n = 0; n < 4; n++)
          acc[m][n] = __builtin_amdgcn_mfma_f32_16x16x32_bf16(af[m], bfv[n], acc[m][n], 0, 0, 0);
    }
    __syncthreads();
  }

  const int rb = bm0 + wm + ((lane >> 4) << 2);
  const int cb = bn0 + wn + (lane & 15);
  if constexpr (EPI == 0) {
#pragma unroll
    for (int m = 0; m < 4; m++)
#pragma unroll
      for (int n = 0; n < 4; n++) {
        int c = cb + n * 16;
        float bv = bias[c];
#pragma unroll
        for (int j = 0; j < 4; j++) {
          int r = rb + m * 16 + j;
          float v = acc[m][n][j] + bv;
          v = 0.5f * v * (1.0f + erff(v * 0.70710678118f));
          Hout[(size_t)r * N + c] = (bf16)v;
        }
      }
  } else {
#pragma unroll
    for (int m = 0; m < 4; m++) {
      float wrow[4];
#pragma unroll
      for (int j = 0; j < 4; j++) wrow[j] = wts[(size_t)(rb + m * 16 + j) * NE + expert];
#pragma unroll
      for (int n = 0; n < 4; n++) {
        int c = cb + n * 16;
        float bv = bias[c];
#pragma unroll
        for (int j = 0; j < 4; j++) {
          int r = rb + m * 16 + j;
          Out[(size_t)r * N + c] += wrow[j] * (acc[m][n][j] + bv);
        }
      }
    }
  }
}

extern "C" void kernel_launch(void* const* d_in, const int* in_sizes, int n_in,
                              void* d_out, int out_size, void* d_ws, size_t ws_size,
                              hipStream_t stream) {
  const float* x  = (const float*)d_in[0];
  const float* gw = (const float*)d_in[1];
  const float* gb = (const float*)d_in[2];
  const float* w1 = (const float*)d_in[3];
  const float* b1 = (const float*)d_in[4];
  const float* w2 = (const float*)d_in[5];
  const float* b2 = (const float*)d_in[6];
  float* out = (float*)d_out;

  char* p = (char*)d_ws;
  bf16* xb   = (bf16*)p;  p += (size_t)NTOK * DM * 2;      // 16.8 MB
  bf16* w1t  = (bf16*)p;  p += (size_t)NE * DM * DH * 2;   // 67 MB  [E][H][D]
  bf16* w2t  = (bf16*)p;  p += (size_t)NE * DM * DH * 2;   // 67 MB  [E][D][H]
  bf16* Hbuf = (bf16*)p;  p += (size_t)NTOK * DH * 2;      // 67 MB
  float* wts = (float*)p; p += (size_t)NTOK * NE * 4;      // 256 KB

  hipMemsetAsync(d_out, 0, (size_t)NTOK * DM * 4, stream);
  convert_x_kernel<<<2048, 256, 0, stream>>>(x, xb, NTOK * DM / 4);
  // w1 [E][DM][DH] -> w1t [E][DH][DM]
  transpose_convert_kernel<<<dim3(DH / 64, DM / 64, NE), 256, 0, stream>>>(w1, w1t, DM, DH);
  // w2 [E][DH][DM] -> w2t [E][DM][DH]
  transpose_convert_kernel<<<dim3(DM / 64, DH / 64, NE), 256, 0, stream>>>(w2, w2t, DH, DM);
  gating_kernel<<<NTOK / 4, 256, 0, stream>>>(x, gw, gb, wts);

  for (int e = 0; e < NE; e++) {
    moe_gemm_kernel<0><<<(NTOK / 128) * (DH / 128), 256, 0, stream>>>(
        xb, w1t + (size_t)e * DH * DM, b1 + (size_t)e * DH,
        Hbuf, nullptr, nullptr, 0, NTOK, DH, DM);
    moe_gemm_kernel<1><<<(NTOK / 128) * (DM / 128), 256, 0, stream>>>(
        Hbuf, w2t + (size_t)e * DM * DH, b2 + (size_t)e * DM,
        nullptr, out, wts, e, NTOK, DM, DH);
  }
}

// Round 2
// 828.176 us; speedup vs baseline: 2.2711x; 2.2711x over previous
//
#include <hip/hip_runtime.h>
#include <hip/hip_bf16.h>
#include <math.h>

#define NTOK   8192   // B*T = 4*2048
#define DM     1024   // d_model
#define DH     4096   // hidden
#define NE     8      // experts
#define CAP    17408  // max gathered rows: 2*NTOK + 8*127, rounded up to 128
#define CAPT   (CAP/128)   // 136 row-tiles

typedef __bf16 bf16;
typedef __bf16 bf16x4 __attribute__((ext_vector_type(4)));
typedef __bf16 bf16x8 __attribute__((ext_vector_type(8)));
typedef float  f32x4  __attribute__((ext_vector_type(4)));

__device__ __forceinline__ void gload16(const void* g, void* l) {
  __builtin_amdgcn_global_load_lds(
      (const __attribute__((address_space(1))) void*)g,
      (__attribute__((address_space(3))) void*)l, 16, 0, 0);
}

// ---------------- fp32 -> bf16 elementwise (x) ----------------
__global__ void convert_x_kernel(const float* __restrict__ src,
                                 bf16* __restrict__ dst, int n4) {
  int stride = gridDim.x * blockDim.x;
  for (int i = blockIdx.x * blockDim.x + threadIdx.x; i < n4; i += stride) {
    float4 v = reinterpret_cast<const float4*>(src)[i];
    bf16x4 o;
    o[0] = (bf16)v.x; o[1] = (bf16)v.y; o[2] = (bf16)v.z; o[3] = (bf16)v.w;
    reinterpret_cast<bf16x4*>(dst)[i] = o;
  }
}

// ------------- fp32 [E][R][C] -> bf16 [E][C][R] tiled transpose -------------
__global__ void transpose_convert_kernel(const float* __restrict__ src,
                                         bf16* __restrict__ dst, int R, int C) {
  __shared__ bf16 tile[64][66];
  int e = blockIdx.z;
  src += (size_t)e * R * C;
  dst += (size_t)e * R * C;
  int c0 = blockIdx.x * 64;
  int r0 = blockIdx.y * 64;
  int lr = threadIdx.x >> 6;   // 0..3
  int lc = threadIdx.x & 63;
#pragma unroll
  for (int i = 0; i < 16; i++) {
    int r = lr + i * 4;
    tile[r][lc] = (bf16)src[(size_t)(r0 + r) * C + c0 + lc];
  }
  __syncthreads();
#pragma unroll
  for (int i = 0; i < 16; i++) {
    int r = lr + i * 4;  // row of dst block (= src col)
    dst[(size_t)(c0 + r) * R + r0 + lc] = tile[lc][r];
  }
}

// -------- gating: logits -> top2 -> softmax -> assignments + counts --------
__global__ void gating_kernel(const float* __restrict__ x,
                              const float* __restrict__ gw,
                              const float* __restrict__ gb,
                              int* __restrict__ assignE,
                              float2* __restrict__ assignW,
                              int* __restrict__ counts) {
  int wave = threadIdx.x >> 6, lane = threadIdx.x & 63;
  int t = blockIdx.x * 4 + wave;
  const float* xr = x + (size_t)t * DM;
  float acc[8];
#pragma unroll
  for (int e = 0; e < 8; e++) acc[e] = 0.f;
#pragma unroll
  for (int i = 0; i < 16; i++) {
    int d = lane + i * 64;
    float xv = xr[d];
    const float4* g = reinterpret_cast<const float4*>(gw + d * 8);
    float4 g0 = g[0], g1 = g[1];
    acc[0] += xv * g0.x; acc[1] += xv * g0.y; acc[2] += xv * g0.z; acc[3] += xv * g0.w;
    acc[4] += xv * g1.x; acc[5] += xv * g1.y; acc[6] += xv * g1.z; acc[7] += xv * g1.w;
  }
#pragma unroll
  for (int off = 32; off > 0; off >>= 1)
#pragma unroll
    for (int e = 0; e < 8; e++) acc[e] += __shfl_xor(acc[e], off, 64);
  if (lane == 0) {
    float v[8];
#pragma unroll
    for (int e = 0; e < 8; e++) v[e] = acc[e] + gb[e];
    int i0 = 0; float v0 = v[0];
#pragma unroll
    for (int e = 1; e < 8; e++) if (v[e] > v0) { v0 = v[e]; i0 = e; }
    int i1 = -1; float v1 = -1e30f;
#pragma unroll
    for (int e = 0; e < 8; e++) if (e != i0 && v[e] > v1) { v1 = v[e]; i1 = e; }
    float p1 = expf(v1 - v0);
    float den = 1.f + p1;
    assignE[t] = i0 | (i1 << 8);
    assignW[t] = make_float2(1.f / den, p1 / den);
    atomicAdd(&counts[i0], 1);
    atomicAdd(&counts[i1], 1);
  }
}

// ---- scan: counts -> 128-aligned segment offsets + tile->expert LUT ----
__global__ void scan_kernel(const int* __restrict__ counts,
                            int* __restrict__ poff,
                            int* __restrict__ tileExpert) {
  if (threadIdx.x == 0 && blockIdx.x == 0) {
    int off = 0;
    for (int e = 0; e < NE; e++) {
      poff[e] = off;
      off += ((counts[e] + 127) >> 7) << 7;
    }
    poff[NE] = off;
    for (int i = 0; i < CAPT; i++) {
      int r = i * 128, ex = -1;
      for (int e = 0; e < NE; e++)
        if (r >= poff[e] && r < poff[e + 1]) ex = e;
      tileExpert[i] = ex;
    }
  }
}

// ---- build: scatter (token, weight, slot) into gathered row table ----
__global__ void build_kernel(const int* __restrict__ assignE,
                             const float2* __restrict__ assignW,
                             const int* __restrict__ poff,
                             int* __restrict__ cursor,
                             int* __restrict__ rowTok,
                             float* __restrict__ rowW,
                             int* __restrict__ rowSlot) {
  int t = blockIdx.x * blockDim.x + threadIdx.x;
  if (t >= NTOK) return;
  int ae = assignE[t];
  float2 aw = assignW[t];
  int e0 = ae & 255, e1 = (ae >> 8) & 255;
  int p0 = poff[e0] + atomicAdd(&cursor[e0], 1);
  rowTok[p0] = t; rowW[p0] = aw.x; rowSlot[p0] = 0;
  int p1 = poff[e1] + atomicAdd(&cursor[e1], 1);
  rowTok[p1] = t; rowW[p1] = aw.y; rowSlot[p1] = 1;
}

// ---------------- grouped bf16 MFMA GEMM over expert segments ----------------
// EPI==0: A gathered via rowTok; Hout[r,n] = gelu(C + bias[n])  (bf16)
// EPI==1: A direct; scatter OutS[slot][tok][n] = w * (C + bias[n])  (fp32)
template <int EPI>
__global__ __launch_bounds__(256) void moe_gemm_kernel(
    const bf16* __restrict__ A, const bf16* __restrict__ Bt,
    const float* __restrict__ bias, bf16* __restrict__ Hout,
    float* __restrict__ OutS,
    const int* __restrict__ rowTok, const float* __restrict__ rowW,
    const int* __restrict__ rowSlot, const int* __restrict__ tileExpert,
    int N, int K) {
  constexpr int BM = 128, BN = 128, BK = 64;
  __shared__ __align__(16) bf16 As[BM * BK];
  __shared__ __align__(16) bf16 Bs[BN * BK];
  const int tid = threadIdx.x;
  const int wave = tid >> 6, lane = tid & 63;
  const int nbn = N / BN;
  const int rt = blockIdx.x / nbn;
  const int e = tileExpert[rt];
  if (e < 0) return;
  const int bm0 = rt * BM;
  const int bn0 = (int)(blockIdx.x % nbn) * BN;
  const int wm = (wave >> 1) * 64, wn = (wave & 1) * 64;
  const bf16* Be = Bt + (size_t)e * N * K;
  const float* be = bias + (size_t)e * N;

  f32x4 acc[4][4];
#pragma unroll
  for (int m = 0; m < 4; m++)
#pragma unroll
    for (int n = 0; n < 4; n++)
#pragma unroll
      for (int j = 0; j < 4; j++) acc[m][n][j] = 0.f;

  const int srow = lane >> 3;            // 0..7 within an 8-row chunk
  const int scolb = (lane & 7) << 4;     // byte col 0..112

  // hoist per-thread row base pointers (rows fixed across K-loop)
  const char* gaBase[4];
  const char* gbBase[4];
#pragma unroll
  for (int it = 0; it < 4; it++) {
    int chunk = it * 4 + wave;
    int row = chunk * 8 + srow;
    int csw = scolb ^ ((row & 7) << 4);
    size_t arow;
    if constexpr (EPI == 0) {
      int tok = rowTok[bm0 + row];
      arow = (size_t)(tok < 0 ? 0 : tok);
    } else {
      arow = (size_t)(bm0 + row);
    }
    gaBase[it] = (const char*)A + arow * (size_t)K * 2 + csw;
    gbBase[it] = (const char*)Be + ((size_t)(bn0 + row)) * K * 2 + csw;
  }

  for (int kt = 0; kt < K; kt += BK) {
#pragma unroll
    for (int it = 0; it < 4; it++) {
      int chunk = it * 4 + wave;
      gload16(gaBase[it] + (size_t)kt * 2, (char*)As + chunk * 1024);
      gload16(gbBase[it] + (size_t)kt * 2, (char*)Bs + chunk * 1024);
    }
    __syncthreads();
#pragma unroll
    for (int kk = 0; kk < 2; kk++) {
      const int kb = kk * 64 + ((lane >> 4) << 4);  // byte offset of k in row
      bf16x8 af[4], bfv[4];
#pragma unroll
      for (int m = 0; m < 4; m++) {
        int r = wm + m * 16 + (lane & 15);
        af[m] = *(const bf16x8*)((const char*)As + r * 128 + (kb ^ ((r & 7) << 4)));
      }
#pragma unroll
      for (int n = 0; n < 4; n++) {
        int r = wn + n * 16 + (lane & 15);
        bfv[n] = *(const bf16x8*)((const char*)Bs + r * 128 + (kb ^ ((r & 7) << 4)));
      }
#pragma unroll
      for (int m = 0; m < 4; m++)
#pragma unroll
        for (int n = 0; n < 4; n++)
          acc[m][n] = __builtin_amdgcn_mfma_f32_16x16x32_bf16(af[m], bfv[n], acc[m][n], 0, 0, 0);
    }
    __syncthreads();
  }

  const int rb = bm0 + wm + ((lane >> 4) << 2);
  const int cb = bn0 + wn + (lane & 15);
  if constexpr (EPI == 0) {
#pragma unroll
    for (int m = 0; m < 4; m++)
#pragma unroll
      for (int n = 0; n < 4; n++) {
        int c = cb + n * 16;
        float bv = be[c];
#pragma unroll
        for (int j = 0; j < 4; j++) {
          int r = rb + m * 16 + j;
          float v = acc[m][n][j] + bv;
          v = 0.5f * v * (1.0f + erff(v * 0.70710678118f));
          Hout[(size_t)r * N + c] = (bf16)v;
        }
      }
  } else {
#pragma unroll
    for (int m = 0; m < 4; m++) {
#pragma unroll
      for (int j = 0; j < 4; j++) {
        int r = rb + m * 16 + j;
        int tok = rowTok[r];
        if (tok < 0) continue;
        float w = rowW[r];
        float* orow = OutS + (size_t)rowSlot[r] * NTOK * DM + (size_t)tok * DM;
#pragma unroll
        for (int n = 0; n < 4; n++) {
          int c = cb + n * 16;
          orow[c] = w * (acc[m][n][j] + be[c]);
        }
      }
    }
  }
}

// ---------------- combine: out = slot0 + slot1 ----------------
__global__ void combine_kernel(const float* __restrict__ s,
                               float* __restrict__ out, int n4) {
  int stride = gridDim.x * blockDim.x;
  const float4* a = (const float4*)s;
  const float4* b = (const float4*)(s + (size_t)NTOK * DM);
  float4* o = (float4*)out;
  for (int i = blockIdx.x * blockDim.x + threadIdx.x; i < n4; i += stride) {
    float4 u = a[i], v = b[i];
    o[i] = make_float4(u.x + v.x, u.y + v.y, u.z + v.z, u.w + v.w);
  }
}

extern "C" void kernel_launch(void* const* d_in, const int* in_sizes, int n_in,
                              void* d_out, int out_size, void* d_ws, size_t ws_size,
                              hipStream_t stream) {
  const float* x  = (const float*)d_in[0];
  const float* gw = (const float*)d_in[1];
  const float* gb = (const float*)d_in[2];
  const float* w1 = (const float*)d_in[3];
  const float* b1 = (const float*)d_in[4];
  const float* w2 = (const float*)d_in[5];
  const float* b2 = (const float*)d_in[6];
  float* out = (float*)d_out;

  char* p = (char*)d_ws;
  bf16* xb   = (bf16*)p;  p += (size_t)NTOK * DM * 2;      // 16.8 MB (dead after GEMM1)
  bf16* w1t  = (bf16*)p;  p += (size_t)NE * DM * DH * 2;   // 67 MB   (dead after GEMM1)
  bf16* Hg   = (bf16*)p;  p += (size_t)CAP * DH * 2;       // 142.6 MB
  bf16* w2t  = (bf16*)p;  p += (size_t)NE * DM * DH * 2;   // 67 MB
  int*   assignE = (int*)p;    p += (size_t)NTOK * 4;
  float2* assignW = (float2*)p; p += (size_t)NTOK * 8;
  int*   rowTok = (int*)p;     p += (size_t)CAP * 4;
  float* rowW   = (float*)p;   p += (size_t)CAP * 4;
  int*   rowSlot = (int*)p;    p += (size_t)CAP * 4;
  int*   counts = (int*)p;     p += 64;   // 8 counts
  int*   cursor = (int*)p;     p += 64;   // 8 cursors
  int*   poff   = (int*)p;     p += 64;   // 9 offsets
  int*   tileExpert = (int*)p; p += (size_t)CAPT * 4;
  float* OutS = (float*)d_ws;  // 67 MB, aliases xb+w1t (both dead when GEMM2 runs)

  hipMemsetAsync(counts, 0, 128, stream);           // counts + cursor
  hipMemsetAsync(rowTok, 0xFF, (size_t)CAP * 4, stream);  // pads = -1

  convert_x_kernel<<<2048, 256, 0, stream>>>(x, xb, NTOK * DM / 4);
  // w1 [E][DM][DH] -> w1t [E][DH][DM]
  transpose_convert_kernel<<<dim3(DH / 64, DM / 64, NE), 256, 0, stream>>>(w1, w1t, DM, DH);
  // w2 [E][DH][DM] -> w2t [E][DM][DH]
  transpose_convert_kernel<<<dim3(DM / 64, DH / 64, NE), 256, 0, stream>>>(w2, w2t, DH, DM);
  gating_kernel<<<NTOK / 4, 256, 0, stream>>>(x, gw, gb, assignE, assignW, counts);
  scan_kernel<<<1, 64, 0, stream>>>(counts, poff, tileExpert);
  build_kernel<<<NTOK / 256, 256, 0, stream>>>(assignE, assignW, poff, cursor,
                                               rowTok, rowW, rowSlot);

  // GEMM1: gathered x @ w1^T -> gelu -> Hg   [CAP x DH]
  moe_gemm_kernel<0><<<CAPT * (DH / 128), 256, 0, stream>>>(
      xb, w1t, b1, Hg, nullptr, rowTok, nullptr, nullptr, tileExpert, DH, DM);
  // GEMM2: Hg @ w2^T -> scatter w*(y+b2) -> OutS[2][NTOK][DM]
  moe_gemm_kernel<1><<<CAPT * (DM / 128), 256, 0, stream>>>(
      Hg, w2t, b2, nullptr, OutS, rowTok, rowW, rowSlot, tileExpert, DM, DH);

  combine_kernel<<<2048, 256, 0, stream>>>(OutS, out, NTOK * DM / 4);
}

// Round 3
// 788.295 us; speedup vs baseline: 2.3860x; 1.0506x over previous
//
#include <hip/hip_runtime.h>
#include <hip/hip_bf16.h>
#include <math.h>

#define NTOK   8192   // B*T = 4*2048
#define DM     1024   // d_model
#define DH     4096   // hidden
#define NE     8      // experts
#define CAP    17408  // max gathered rows: 2*NTOK + 8*127, rounded up to 128
#define CAPT   (CAP/128)   // 136 row-tiles

typedef __bf16 bf16;
typedef __bf16 bf16x4 __attribute__((ext_vector_type(4)));
typedef __bf16 bf16x8 __attribute__((ext_vector_type(8)));
typedef float  f32x4  __attribute__((ext_vector_type(4)));

__device__ __forceinline__ void gload16(const void* g, void* l) {
  __builtin_amdgcn_global_load_lds(
      (const __attribute__((address_space(1))) void*)g,
      (__attribute__((address_space(3))) void*)l, 16, 0, 0);
}

// fast GELU (tanh form): v * sigmoid(1.5957691216*(v + 0.044715 v^3))*... 
// gelu(v) ~= v / (1 + exp(-2*0.7978845608*(v + 0.044715*v^3)))
__device__ __forceinline__ float gelu_f(float v) {
  float u = v * v * v;
  float t = 1.5957691216f * v + 0.0713548162726f * u;
  float e = __expf(-t);
  return v * __builtin_amdgcn_rcpf(1.0f + e);
}

// ------------- fp32 [E][R][C] -> bf16 [E][C][R] tiled transpose -------------
__global__ void transpose_convert_kernel(const float* __restrict__ src,
                                         bf16* __restrict__ dst, int R, int C) {
  __shared__ bf16 tile[64][66];
  int e = blockIdx.z;
  src += (size_t)e * R * C;
  dst += (size_t)e * R * C;
  int c0 = blockIdx.x * 64;
  int r0 = blockIdx.y * 64;
  int lr = threadIdx.x >> 6;   // 0..3
  int lc = threadIdx.x & 63;
#pragma unroll
  for (int i = 0; i < 16; i++) {
    int r = lr + i * 4;
    tile[r][lc] = (bf16)src[(size_t)(r0 + r) * C + c0 + lc];
  }
  __syncthreads();
#pragma unroll
  for (int i = 0; i < 16; i++) {
    int r = lr + i * 4;  // row of dst block (= src col)
    dst[(size_t)(c0 + r) * R + r0 + lc] = tile[lc][r];
  }
}

// -- gating fused with x->bf16 convert: logits -> top2 -> softmax + counts --
__global__ void gating_kernel(const float* __restrict__ x,
                              const float* __restrict__ gw,
                              const float* __restrict__ gb,
                              bf16* __restrict__ xb,
                              int* __restrict__ assignE,
                              float2* __restrict__ assignW,
                              int* __restrict__ counts) {
  int wave = threadIdx.x >> 6, lane = threadIdx.x & 63;
  int t = blockIdx.x * 4 + wave;
  const float* xr = x + (size_t)t * DM;
  // each lane owns 16 contiguous d: [lane*16, lane*16+16)
  float4 xv[4];
  const float4* xr4 = reinterpret_cast<const float4*>(xr) + lane * 4;
#pragma unroll
  for (int i = 0; i < 4; i++) xv[i] = xr4[i];
  // convert + store bf16 x
#pragma unroll
  for (int i = 0; i < 2; i++) {
    float4 a = xv[2 * i], b = xv[2 * i + 1];
    bf16x8 o;
    o[0] = (bf16)a.x; o[1] = (bf16)a.y; o[2] = (bf16)a.z; o[3] = (bf16)a.w;
    o[4] = (bf16)b.x; o[5] = (bf16)b.y; o[6] = (bf16)b.z; o[7] = (bf16)b.w;
    reinterpret_cast<bf16x8*>(xb + (size_t)t * DM)[lane * 2 + i] = o;
  }
  // gate logits
  float acc[8];
#pragma unroll
  for (int e = 0; e < 8; e++) acc[e] = 0.f;
  int d0 = lane * 16;
#pragma unroll
  for (int j = 0; j < 16; j++) {
    float xvj = reinterpret_cast<const float*>(xv)[j];
    const float4* g = reinterpret_cast<const float4*>(gw + (size_t)(d0 + j) * 8);
    float4 g0 = g[0], g1 = g[1];
    acc[0] += xvj * g0.x; acc[1] += xvj * g0.y; acc[2] += xvj * g0.z; acc[3] += xvj * g0.w;
    acc[4] += xvj * g1.x; acc[5] += xvj * g1.y; acc[6] += xvj * g1.z; acc[7] += xvj * g1.w;
  }
#pragma unroll
  for (int off = 32; off > 0; off >>= 1)
#pragma unroll
    for (int e = 0; e < 8; e++) acc[e] += __shfl_xor(acc[e], off, 64);
  if (lane == 0) {
    float v[8];
#pragma unroll
    for (int e = 0; e < 8; e++) v[e] = acc[e] + gb[e];
    int i0 = 0; float v0 = v[0];
#pragma unroll
    for (int e = 1; e < 8; e++) if (v[e] > v0) { v0 = v[e]; i0 = e; }
    int i1 = -1; float v1 = -1e30f;
#pragma unroll
    for (int e = 0; e < 8; e++) if (e != i0 && v[e] > v1) { v1 = v[e]; i1 = e; }
    float p1 = expf(v1 - v0);
    float den = 1.f + p1;
    assignE[t] = i0 | (i1 << 8);
    assignW[t] = make_float2(1.f / den, p1 / den);
    atomicAdd(&counts[i0], 1);
    atomicAdd(&counts[i1], 1);
  }
}

// ---- scan: counts -> 128-aligned segment offsets + tile->expert LUT ----
__global__ void scan_kernel(const int* __restrict__ counts,
                            int* __restrict__ poff,
                            int* __restrict__ tileExpert) {
  if (threadIdx.x == 0 && blockIdx.x == 0) {
    int off = 0;
    for (int e = 0; e < NE; e++) {
      poff[e] = off;
      off += ((counts[e] + 127) >> 7) << 7;
    }
    poff[NE] = off;
    for (int i = 0; i < CAPT; i++) {
      int r = i * 128, ex = -1;
      for (int e = 0; e < NE; e++)
        if (r >= poff[e] && r < poff[e + 1]) ex = e;
      tileExpert[i] = ex;
    }
  }
}

// ---- build: scatter (token, weight, slot) into gathered row table ----
__global__ void build_kernel(const int* __restrict__ assignE,
                             const float2* __restrict__ assignW,
                             const int* __restrict__ poff,
                             int* __restrict__ cursor,
                             int* __restrict__ rowTok,
                             float* __restrict__ rowW,
                             int* __restrict__ rowSlot) {
  int t = blockIdx.x * blockDim.x + threadIdx.x;
  if (t >= NTOK) return;
  int ae = assignE[t];
  float2 aw = assignW[t];
  int e0 = ae & 255, e1 = (ae >> 8) & 255;
  int p0 = poff[e0] + atomicAdd(&cursor[e0], 1);
  rowTok[p0] = t; rowW[p0] = aw.x; rowSlot[p0] = 0;
  int p1 = poff[e1] + atomicAdd(&cursor[e1], 1);
  rowTok[p1] = t; rowW[p1] = aw.y; rowSlot[p1] = 1;
}

// ---------------- grouped bf16 MFMA GEMM over expert segments ----------------
// EPI==0: A gathered via rowTok; Hout[r,n] = gelu(C + bias[n])  (bf16)
// EPI==1: A direct; scatter OutS[slot][tok][n] = w * (C + bias[n])  (fp32)
template <int EPI>
__global__ __launch_bounds__(256) void moe_gemm_kernel(
    const bf16* __restrict__ A, const bf16* __restrict__ Bt,
    const float* __restrict__ bias, bf16* __restrict__ Hout,
    float* __restrict__ OutS,
    const int* __restrict__ rowTok, const float* __restrict__ rowW,
    const int* __restrict__ rowSlot, const int* __restrict__ tileExpert,
    int N, int K) {
  constexpr int BM = 128, BN = 128, BK = 64;
  __shared__ __align__(16) bf16 As[BM * BK];
  __shared__ __align__(16) bf16 Bs[BN * BK];
  const int tid = threadIdx.x;
  const int wave = tid >> 6, lane = tid & 63;
  const int nbn = N / BN;
  const int rt = blockIdx.x / nbn;
  const int e = tileExpert[rt];
  if (e < 0) return;
  const int bm0 = rt * BM;
  const int bn0 = (int)(blockIdx.x % nbn) * BN;
  const int wm = (wave >> 1) * 64, wn = (wave & 1) * 64;
  const bf16* Be = Bt + (size_t)e * N * K;
  const float* be = bias + (size_t)e * N;

  f32x4 acc[4][4];
#pragma unroll
  for (int m = 0; m < 4; m++)
#pragma unroll
    for (int n = 0; n < 4; n++)
#pragma unroll
      for (int j = 0; j < 4; j++) acc[m][n][j] = 0.f;

  const int srow = lane >> 3;            // 0..7 within an 8-row chunk
  const int scolb = (lane & 7) << 4;     // byte col 0..112

  // hoist per-thread row base pointers (rows fixed across K-loop)
  const char* gaBase[4];
  const char* gbBase[4];
#pragma unroll
  for (int it = 0; it < 4; it++) {
    int chunk = it * 4 + wave;
    int row = chunk * 8 + srow;
    int csw = scolb ^ ((row & 7) << 4);
    size_t arow;
    if constexpr (EPI == 0) {
      int tok = rowTok[bm0 + row];
      arow = (size_t)(tok < 0 ? 0 : tok);
    } else {
      arow = (size_t)(bm0 + row);
    }
    gaBase[it] = (const char*)A + arow * (size_t)K * 2 + csw;
    gbBase[it] = (const char*)Be + ((size_t)(bn0 + row)) * K * 2 + csw;
  }

  for (int kt = 0; kt < K; kt += BK) {
#pragma unroll
    for (int it = 0; it < 4; it++) {
      int chunk = it * 4 + wave;
      gload16(gaBase[it] + (size_t)kt * 2, (char*)As + chunk * 1024);
      gload16(gbBase[it] + (size_t)kt * 2, (char*)Bs + chunk * 1024);
    }
    __syncthreads();
#pragma unroll
    for (int kk = 0; kk < 2; kk++) {
      const int kb = kk * 64 + ((lane >> 4) << 4);  // byte offset of k in row
      bf16x8 af[4], bfv[4];
#pragma unroll
      for (int m = 0; m < 4; m++) {
        int r = wm + m * 16 + (lane & 15);
        af[m] = *(const bf16x8*)((const char*)As + r * 128 + (kb ^ ((r & 7) << 4)));
      }
#pragma unroll
      for (int n = 0; n < 4; n++) {
        int r = wn + n * 16 + (lane & 15);
        bfv[n] = *(const bf16x8*)((const char*)Bs + r * 128 + (kb ^ ((r & 7) << 4)));
      }
#pragma unroll
      for (int m = 0; m < 4; m++)
#pragma unroll
        for (int n = 0; n < 4; n++)
          acc[m][n] = __builtin_amdgcn_mfma_f32_16x16x32_bf16(af[m], bfv[n], acc[m][n], 0, 0, 0);
    }
    __syncthreads();
  }

  const int rb = bm0 + wm + ((lane >> 4) << 2);
  const int cb = bn0 + wn + (lane & 15);
  if constexpr (EPI == 0) {
#pragma unroll
    for (int m = 0; m < 4; m++)
#pragma unroll
      for (int n = 0; n < 4; n++) {
        int c = cb + n * 16;
        float bv = be[c];
#pragma unroll
        for (int j = 0; j < 4; j++) {
          int r = rb + m * 16 + j;
          Hout[(size_t)r * N + c] = (bf16)gelu_f(acc[m][n][j] + bv);
        }
      }
  } else {
#pragma unroll
    for (int m = 0; m < 4; m++) {
#pragma unroll
      for (int j = 0; j < 4; j++) {
        int r = rb + m * 16 + j;
        int tok = rowTok[r];
        if (tok < 0) continue;
        float w = rowW[r];
        float* orow = OutS + (size_t)rowSlot[r] * NTOK * DM + (size_t)tok * DM;
#pragma unroll
        for (int n = 0; n < 4; n++) {
          int c = cb + n * 16;
          orow[c] = w * (acc[m][n][j] + be[c]);
        }
      }
    }
  }
}

// ---------------- combine: out = slot0 + slot1 ----------------
__global__ void combine_kernel(const float* __restrict__ s,
                               float* __restrict__ out, int n4) {
  int stride = gridDim.x * blockDim.x;
  const float4* a = (const float4*)s;
  const float4* b = (const float4*)(s + (size_t)NTOK * DM);
  float4* o = (float4*)out;
  for (int i = blockIdx.x * blockDim.x + threadIdx.x; i < n4; i += stride) {
    float4 u = a[i], v = b[i];
    o[i] = make_float4(u.x + v.x, u.y + v.y, u.z + v.z, u.w + v.w);
  }
}

extern "C" void kernel_launch(void* const* d_in, const int* in_sizes, int n_in,
                              void* d_out, int out_size, void* d_ws, size_t ws_size,
                              hipStream_t stream) {
  const float* x  = (const float*)d_in[0];
  const float* gw = (const float*)d_in[1];
  const float* gb = (const float*)d_in[2];
  const float* w1 = (const float*)d_in[3];
  const float* b1 = (const float*)d_in[4];
  const float* w2 = (const float*)d_in[5];
  const float* b2 = (const float*)d_in[6];
  float* out = (float*)d_out;

  char* p = (char*)d_ws;
  bf16* xb   = (bf16*)p;  p += (size_t)NTOK * DM * 2;      // 16.8 MB (dead after GEMM1)
  bf16* w1t  = (bf16*)p;  p += (size_t)NE * DM * DH * 2;   // 67 MB   (dead after GEMM1)
  bf16* Hg   = (bf16*)p;  p += (size_t)CAP * DH * 2;       // 142.6 MB
  bf16* w2t  = (bf16*)p;  p += (size_t)NE * DM * DH * 2;   // 67 MB
  int*   assignE = (int*)p;    p += (size_t)NTOK * 4;
  float2* assignW = (float2*)p; p += (size_t)NTOK * 8;
  int*   rowTok = (int*)p;     p += (size_t)CAP * 4;
  float* rowW   = (float*)p;   p += (size_t)CAP * 4;
  int*   rowSlot = (int*)p;    p += (size_t)CAP * 4;
  int*   counts = (int*)p;     p += 64;   // 8 counts
  int*   cursor = (int*)p;     p += 64;   // 8 cursors
  int*   poff   = (int*)p;     p += 64;   // 9 offsets
  int*   tileExpert = (int*)p; p += (size_t)CAPT * 4;
  float* OutS = (float*)d_ws;  // 67 MB, aliases xb+w1t (both dead when GEMM2 runs)

  hipMemsetAsync(counts, 0, 128, stream);           // counts + cursor
  hipMemsetAsync(rowTok, 0xFF, (size_t)CAP * 4, stream);  // pads = -1

  // w1 [E][DM][DH] -> w1t [E][DH][DM]
  transpose_convert_kernel<<<dim3(DH / 64, DM / 64, NE), 256, 0, stream>>>(w1, w1t, DM, DH);
  // w2 [E][DH][DM] -> w2t [E][DM][DH]
  transpose_convert_kernel<<<dim3(DM / 64, DH / 64, NE), 256, 0, stream>>>(w2, w2t, DH, DM);
  gating_kernel<<<NTOK / 4, 256, 0, stream>>>(x, gw, gb, xb, assignE, assignW, counts);
  scan_kernel<<<1, 64, 0, stream>>>(counts, poff, tileExpert);
  build_kernel<<<NTOK / 256, 256, 0, stream>>>(assignE, assignW, poff, cursor,
                                               rowTok, rowW, rowSlot);

  // GEMM1: gathered x @ w1^T -> gelu -> Hg   [CAP x DH]
  moe_gemm_kernel<0><<<CAPT * (DH / 128), 256, 0, stream>>>(
      xb, w1t, b1, Hg, nullptr, rowTok, nullptr, nullptr, tileExpert, DH, DM);
  // GEMM2: Hg @ w2^T -> scatter w*(y+b2) -> OutS[2][NTOK][DM]
  moe_gemm_kernel<1><<<CAPT * (DM / 128), 256, 0, stream>>>(
      Hg, w2t, b2, nullptr, OutS, rowTok, rowW, rowSlot, tileExpert, DM, DH);

  combine_kernel<<<2048, 256, 0, stream>>>(OutS, out, NTOK * DM / 4);
}

// Round 4
// 613.387 us; speedup vs baseline: 3.0664x; 1.2852x over previous
//
#include <hip/hip_runtime.h>
#include <hip/hip_bf16.h>
#include <math.h>

#define NTOK   8192   // B*T = 4*2048
#define DM     1024   // d_model
#define DH     4096   // hidden
#define NE     8      // experts
#define CAP    17408  // max gathered rows: 2*NTOK + 8*127, rounded up to 128
#define CAPT   (CAP/128)   // 136 row-tiles

typedef __bf16 bf16;
typedef __bf16 bf16x4 __attribute__((ext_vector_type(4)));
typedef __bf16 bf16x8 __attribute__((ext_vector_type(8)));
typedef float  f32x4  __attribute__((ext_vector_type(4)));

__device__ __forceinline__ void gload16(const void* g, void* l) {
  __builtin_amdgcn_global_load_lds(
      (const __attribute__((address_space(1))) void*)g,
      (__attribute__((address_space(3))) void*)l, 16, 0, 0);
}

// fast GELU (tanh form): gelu(v) ~= v / (1 + exp(-1.5957691216*(v + 0.044715*v^3)*... ))
__device__ __forceinline__ float gelu_f(float v) {
  float u = v * v * v;
  float t = 1.5957691216f * v + 0.0713548162726f * u;
  float e = __expf(-t);
  return v * __builtin_amdgcn_rcpf(1.0f + e);
}

// ------------- fp32 [E][R][C] -> bf16 [E][C][R] tiled transpose -------------
__global__ void transpose_convert_kernel(const float* __restrict__ src,
                                         bf16* __restrict__ dst, int R, int C) {
  __shared__ bf16 tile[64][66];
  int e = blockIdx.z;
  src += (size_t)e * R * C;
  dst += (size_t)e * R * C;
  int c0 = blockIdx.x * 64;
  int r0 = blockIdx.y * 64;
  int lr = threadIdx.x >> 6;   // 0..3
  int lc = threadIdx.x & 63;
#pragma unroll
  for (int i = 0; i < 16; i++) {
    int r = lr + i * 4;
    tile[r][lc] = (bf16)src[(size_t)(r0 + r) * C + c0 + lc];
  }
  __syncthreads();
#pragma unroll
  for (int i = 0; i < 16; i++) {
    int r = lr + i * 4;  // row of dst block (= src col)
    dst[(size_t)(c0 + r) * R + r0 + lc] = tile[lc][r];
  }
}

// -- gating fused with x->bf16 convert: logits -> top2 -> softmax weights --
__global__ void gating_kernel(const float* __restrict__ x,
                              const float* __restrict__ gw,
                              const float* __restrict__ gb,
                              bf16* __restrict__ xb,
                              int* __restrict__ assignE,
                              float2* __restrict__ assignW) {
  int wave = threadIdx.x >> 6, lane = threadIdx.x & 63;
  int t = blockIdx.x * 4 + wave;
  const float* xr = x + (size_t)t * DM;
  // each lane owns 16 contiguous d: [lane*16, lane*16+16)
  float4 xv[4];
  const float4* xr4 = reinterpret_cast<const float4*>(xr) + lane * 4;
#pragma unroll
  for (int i = 0; i < 4; i++) xv[i] = xr4[i];
  // convert + store bf16 x
#pragma unroll
  for (int i = 0; i < 2; i++) {
    float4 a = xv[2 * i], b = xv[2 * i + 1];
    bf16x8 o;
    o[0] = (bf16)a.x; o[1] = (bf16)a.y; o[2] = (bf16)a.z; o[3] = (bf16)a.w;
    o[4] = (bf16)b.x; o[5] = (bf16)b.y; o[6] = (bf16)b.z; o[7] = (bf16)b.w;
    reinterpret_cast<bf16x8*>(xb + (size_t)t * DM)[lane * 2 + i] = o;
  }
  // gate logits
  float acc[8];
#pragma unroll
  for (int e = 0; e < 8; e++) acc[e] = 0.f;
  int d0 = lane * 16;
#pragma unroll
  for (int j = 0; j < 16; j++) {
    float xvj = reinterpret_cast<const float*>(xv)[j];
    const float4* g = reinterpret_cast<const float4*>(gw + (size_t)(d0 + j) * 8);
    float4 g0 = g[0], g1 = g[1];
    acc[0] += xvj * g0.x; acc[1] += xvj * g0.y; acc[2] += xvj * g0.z; acc[3] += xvj * g0.w;
    acc[4] += xvj * g1.x; acc[5] += xvj * g1.y; acc[6] += xvj * g1.z; acc[7] += xvj * g1.w;
  }
#pragma unroll
  for (int off = 32; off > 0; off >>= 1)
#pragma unroll
    for (int e = 0; e < 8; e++) acc[e] += __shfl_xor(acc[e], off, 64);
  if (lane == 0) {
    float v[8];
#pragma unroll
    for (int e = 0; e < 8; e++) v[e] = acc[e] + gb[e];
    int i0 = 0; float v0 = v[0];
#pragma unroll
    for (int e = 1; e < 8; e++) if (v[e] > v0) { v0 = v[e]; i0 = e; }
    int i1 = -1; float v1 = -1e30f;
#pragma unroll
    for (int e = 0; e < 8; e++) if (e != i0 && v[e] > v1) { v1 = v[e]; i1 = e; }
    float p1 = expf(v1 - v0);
    float den = 1.f + p1;
    assignE[t] = i0 | (i1 << 8);
    assignW[t] = make_float2(1.f / den, p1 / den);
  }
}

// ---- router (single block): histogram -> 128-aligned offsets -> LUT -> scatter ----
__global__ void router_kernel(const int* __restrict__ assignE,
                              const float2* __restrict__ assignW,
                              int* __restrict__ rowTok,
                              float* __restrict__ rowW,
                              int* __restrict__ tileExpert) {
  __shared__ int cnt[NE], off[NE + 1], cur[NE];
  int tid = threadIdx.x;
  if (tid < NE) cnt[tid] = 0;
  __syncthreads();
  for (int t = tid; t < NTOK; t += 256) {
    int ae = assignE[t];
    atomicAdd(&cnt[ae & 255], 1);
    atomicAdd(&cnt[(ae >> 8) & 255], 1);
  }
  __syncthreads();
  if (tid == 0) {
    int o = 0;
    for (int e = 0; e < NE; e++) { off[e] = o; o += ((cnt[e] + 127) >> 7) << 7; }
    off[NE] = o;
  }
  __syncthreads();
  if (tid < NE) cur[tid] = 0;
  for (int i = tid; i < CAPT; i += 256) {
    int r = i * 128, ex = -1;
#pragma unroll
    for (int e = 0; e < NE; e++)
      if (r >= off[e] && r < off[e + 1]) ex = e;
    tileExpert[i] = ex;
  }
  for (int i = tid; i < CAP; i += 256) rowTok[i] = -1;
  __syncthreads();
  for (int t = tid; t < NTOK; t += 256) {
    int ae = assignE[t];
    float2 aw = assignW[t];
    int e0 = ae & 255, e1 = (ae >> 8) & 255;
    int p0 = off[e0] + atomicAdd(&cur[e0], 1);
    rowTok[p0] = t; rowW[p0] = aw.x;
    int p1 = off[e1] + atomicAdd(&cur[e1], 1);
    rowTok[p1] = t; rowW[p1] = aw.y;
  }
}

// ---------------- grouped bf16 MFMA GEMM over expert segments ----------------
// EPI==0: A gathered via rowTok; Hout[r,n] = gelu(C + bias[n])  (bf16)
// EPI==1: A direct; atomicAdd Out[tok][n] += w * (C + bias[n])  (fp32, 2 adds/cell)
template <int EPI>
__global__ __launch_bounds__(256) void moe_gemm_kernel(
    const bf16* __restrict__ A, const bf16* __restrict__ Bt,
    const float* __restrict__ bias, bf16* __restrict__ Hout,
    float* __restrict__ Out,
    const int* __restrict__ rowTok, const float* __restrict__ rowW,
    const int* __restrict__ tileExpert,
    int N, int K) {
  constexpr int BM = 128, BN = 128, BK = 64;
  __shared__ __align__(16) bf16 As[BM * BK];
  __shared__ __align__(16) bf16 Bs[BN * BK];
  const int tid = threadIdx.x;
  const int wave = tid >> 6, lane = tid & 63;
  const int nbn = N / BN;
  // XCD-chunked bijective swizzle (grid divisible by 8): blocks sharing an
  // A row-tile become adjacent logical ids on the SAME XCD -> L2 reuse.
  const int nwg = (int)gridDim.x;
  const int bid = (int)blockIdx.x;
  const int swz = (bid & 7) * (nwg >> 3) + (bid >> 3);
  const int rt = swz / nbn;
  const int e = tileExpert[rt];
  if (e < 0) return;
  const int bm0 = rt * BM;
  const int bn0 = (swz % nbn) * BN;
  const int wm = (wave >> 1) * 64, wn = (wave & 1) * 64;
  const bf16* Be = Bt + (size_t)e * N * K;
  const float* be = bias + (size_t)e * N;

  f32x4 acc[4][4];
#pragma unroll
  for (int m = 0; m < 4; m++)
#pragma unroll
    for (int n = 0; n < 4; n++)
#pragma unroll
      for (int j = 0; j < 4; j++) acc[m][n][j] = 0.f;

  const int srow = lane >> 3;            // 0..7 within an 8-row chunk
  const int scolb = (lane & 7) << 4;     // byte col 0..112

  // hoist per-thread row base pointers (rows fixed across K-loop)
  const char* gaBase[4];
  const char* gbBase[4];
#pragma unroll
  for (int it = 0; it < 4; it++) {
    int chunk = it * 4 + wave;
    int row = chunk * 8 + srow;
    int csw = scolb ^ ((row & 7) << 4);
    size_t arow;
    if constexpr (EPI == 0) {
      int tok = rowTok[bm0 + row];
      arow = (size_t)(tok < 0 ? 0 : tok);
    } else {
      arow = (size_t)(bm0 + row);
    }
    gaBase[it] = (const char*)A + arow * (size_t)K * 2 + csw;
    gbBase[it] = (const char*)Be + ((size_t)(bn0 + row)) * K * 2 + csw;
  }

  for (int kt = 0; kt < K; kt += BK) {
#pragma unroll
    for (int it = 0; it < 4; it++) {
      int chunk = it * 4 + wave;
      gload16(gaBase[it] + (size_t)kt * 2, (char*)As + chunk * 1024);
      gload16(gbBase[it] + (size_t)kt * 2, (char*)Bs + chunk * 1024);
    }
    __syncthreads();
#pragma unroll
    for (int kk = 0; kk < 2; kk++) {
      const int kb = kk * 64 + ((lane >> 4) << 4);  // byte offset of k in row
      bf16x8 af[4], bfv[4];
#pragma unroll
      for (int m = 0; m < 4; m++) {
        int r = wm + m * 16 + (lane & 15);
        af[m] = *(const bf16x8*)((const char*)As + r * 128 + (kb ^ ((r & 7) << 4)));
      }
#pragma unroll
      for (int n = 0; n < 4; n++) {
        int r = wn + n * 16 + (lane & 15);
        bfv[n] = *(const bf16x8*)((const char*)Bs + r * 128 + (kb ^ ((r & 7) << 4)));
      }
#pragma unroll
      for (int m = 0; m < 4; m++)
#pragma unroll
        for (int n = 0; n < 4; n++)
          acc[m][n] = __builtin_amdgcn_mfma_f32_16x16x32_bf16(af[m], bfv[n], acc[m][n], 0, 0, 0);
    }
    __syncthreads();
  }

  const int rb = bm0 + wm + ((lane >> 4) << 2);
  const int cb = bn0 + wn + (lane & 15);
  if constexpr (EPI == 0) {
#pragma unroll
    for (int m = 0; m < 4; m++)
#pragma unroll
      for (int n = 0; n < 4; n++) {
        int c = cb + n * 16;
        float bv = be[c];
#pragma unroll
        for (int j = 0; j < 4; j++) {
          int r = rb + m * 16 + j;
          Hout[(size_t)r * N + c] = (bf16)gelu_f(acc[m][n][j] + bv);
        }
      }
  } else {
#pragma unroll
    for (int m = 0; m < 4; m++) {
#pragma unroll
      for (int j = 0; j < 4; j++) {
        int r = rb + m * 16 + j;
        int tok = rowTok[r];
        if (tok < 0) continue;
        float w = rowW[r];
        float* orow = Out + (size_t)tok * DM;
#pragma unroll
        for (int n = 0; n < 4; n++) {
          int c = cb + n * 16;
          atomicAdd(&orow[c], w * (acc[m][n][j] + be[c]));
        }
      }
    }
  }
}

extern "C" void kernel_launch(void* const* d_in, const int* in_sizes, int n_in,
                              void* d_out, int out_size, void* d_ws, size_t ws_size,
                              hipStream_t stream) {
  const float* x  = (const float*)d_in[0];
  const float* gw = (const float*)d_in[1];
  const float* gb = (const float*)d_in[2];
  const float* w1 = (const float*)d_in[3];
  const float* b1 = (const float*)d_in[4];
  const float* w2 = (const float*)d_in[5];
  const float* b2 = (const float*)d_in[6];
  float* out = (float*)d_out;

  char* p = (char*)d_ws;
  bf16* xb   = (bf16*)p;  p += (size_t)NTOK * DM * 2;      // 16.8 MB
  bf16* w1t  = (bf16*)p;  p += (size_t)NE * DM * DH * 2;   // 67 MB  [E][H][D]
  bf16* Hg   = (bf16*)p;  p += (size_t)CAP * DH * 2;       // 142.6 MB
  bf16* w2t  = (bf16*)p;  p += (size_t)NE * DM * DH * 2;   // 67 MB  [E][D][H]
  int*   assignE = (int*)p;     p += (size_t)NTOK * 4;
  float2* assignW = (float2*)p; p += (size_t)NTOK * 8;
  int*   rowTok = (int*)p;      p += (size_t)CAP * 4;
  float* rowW   = (float*)p;    p += (size_t)CAP * 4;
  int*   tileExpert = (int*)p;  p += (size_t)CAPT * 4;

  // out accumulated via atomics -> must be zeroed every call
  hipMemsetAsync(d_out, 0, (size_t)NTOK * DM * 4, stream);

  // w1 [E][DM][DH] -> w1t [E][DH][DM]
  transpose_convert_kernel<<<dim3(DH / 64, DM / 64, NE), 256, 0, stream>>>(w1, w1t, DM, DH);
  // w2 [E][DH][DM] -> w2t [E][DM][DH]
  transpose_convert_kernel<<<dim3(DM / 64, DH / 64, NE), 256, 0, stream>>>(w2, w2t, DH, DM);
  gating_kernel<<<NTOK / 4, 256, 0, stream>>>(x, gw, gb, xb, assignE, assignW);
  router_kernel<<<1, 256, 0, stream>>>(assignE, assignW, rowTok, rowW, tileExpert);

  // GEMM1: gathered x @ w1^T -> gelu -> Hg   [CAP x DH]
  moe_gemm_kernel<0><<<CAPT * (DH / 128), 256, 0, stream>>>(
      xb, w1t, b1, Hg, nullptr, rowTok, nullptr, tileExpert, DH, DM);
  // GEMM2: Hg @ w2^T -> atomic scatter w*(y+b2) into out
  moe_gemm_kernel<1><<<CAPT * (DM / 128), 256, 0, stream>>>(
      Hg, w2t, b2, nullptr, out, rowTok, rowW, tileExpert, DM, DH);
}